// Round 10
// baseline (38.461 us; speedup 1.0000x reference)
//
#include <hip/hip_runtime.h>

#define HID 128
#define FEAT 16
#define N_PER 100000
#define NUM_ACTIONS 75000
#define N_NODES 100000
#define N_GRAPHS 512

// ws float layout:
// [0..143]   wg   (globs part 0..127, feat part 128..143)
// [144..287] wn   (nodes part 144..271, feat part 272..287)
// [288..415] qe
// [416..687] w1   (row 416..543, feat 544..559, col 560..687)
// [688] cg [689] cn [690] ce [691] pb
// [NSCAL_OFF + 4h]  nscal(h): (x=nodes.wr, y=nodes.wc, z=nodes.wn)
// [GSCAL_OFF + u]   gscal(u) = globs[u].wg
// [ESCAL_OFF + g]   escal(g) = edges[E[g]].qe
// [PSUM_OFF + a]    psum(a)  = per-action feat-dot partial
#define NSCAL_OFF 1024
#define GSCAL_OFF (NSCAL_OFF + 4 * N_NODES)
#define ESCAL_OFF (GSCAL_OFF + N_GRAPHS)
#define PSUM_OFF  (ESCAL_OFF + N_PER)

#define NB 720
#define EB 1040
#define FB 256
#define GB 16
#define WORK_BLOCKS (NB + EB + FB + GB)

__device__ __forceinline__ float dot4(float4 a, float4 b) {
    return a.x * b.x + a.y * b.y + a.z * b.z + a.w * b.w;
}

// ---- DPP sum reductions (VALU-only, no LDS pipe) ----
template <int CTRL>
__device__ __forceinline__ float dpp_mov(float x) {
    return __int_as_float(__builtin_amdgcn_update_dpp(
        0, __float_as_int(x), CTRL, 0xF, 0xF, true));
}
__device__ __forceinline__ float red16(float x) {
    x += dpp_mov<0x111>(x);   // row_shr:1
    x += dpp_mov<0x112>(x);   // row_shr:2
    x += dpp_mov<0x114>(x);   // row_shr:4
    x += dpp_mov<0x118>(x);   // row_shr:8
    return x;                 // valid in lane 15 (mod 16)
}
__device__ __forceinline__ float red32(float x) {
    x = red16(x);
    x += dpp_mov<0x142>(x);   // row_bcast:15
    return x;                 // valid in lane 31 (mod 32)
}
__device__ __forceinline__ float red64(float x) {
    x = red32(x);
    x += dpp_mov<0x143>(x);   // row_bcast:31
    return x;                 // valid in lane 63
}

// 44 blocks x 1024 threads (proven R6 version). Blocks 26..43 build qEE in
// LDS; each wave then does <=1 of the 692 folded dots.
__global__ __launch_bounds__(1024) void fold_kernel(
    const float* __restrict__ glob_W, const float* __restrict__ glob_b,
    const float* __restrict__ node_W, const float* __restrict__ node_b,
    const float* __restrict__ e1_W,  const float* __restrict__ e1_b,
    const float* __restrict__ e2_W,  const float* __restrict__ e2_b,
    const float* __restrict__ pol_W, const float* __restrict__ pol_b,
    float* __restrict__ ws)
{
    __shared__ float qEE[HID];
    const int t = threadIdx.x, wave = t >> 6, lane = t & 63;
    const int bid = blockIdx.x;

    const bool needq = (bid >= 26 && bid <= 43);
    if (needq) {
        const int hw = t >> 5, s = t & 31;
        const float4 p4 = *(const float4*)&pol_W[4 * s];
        #pragma unroll
        for (int r = 0; r < 4; ++r) {
            const int k = hw + 32 * r;
            const float4 x = *(const float4*)&e2_W[(HID + k) * HID + 4 * s];
            float acc = red32(dot4(x, p4));
            if (s == 31) qEE[k] = acc;
        }
        __syncthreads();
    }

    const float2 p2 = *(const float2*)&pol_W[2 * lane];
    const int d = bid * 16 + wave;
    if (d == 691) {
        if (lane == 0) ws[691] = pol_b[0];
    } else if (d < 692) {
        float acc;
        if (d < 144) {
            const float2 x = *(const float2*)&glob_W[d * HID + 2 * lane];
            acc = x.x * p2.x + x.y * p2.y;
        } else if (d < 288) {
            const float2 x = *(const float2*)&node_W[(d - 144) * HID + 2 * lane];
            acc = x.x * p2.x + x.y * p2.y;
        } else if (d < 416) {
            const float2 x = *(const float2*)&e2_W[(d - 288) * HID + 2 * lane];
            acc = x.x * p2.x + x.y * p2.y;
        } else if (d < 688) {
            const float2 q2 = *(const float2*)&qEE[2 * lane];
            const float2 x  = *(const float2*)&e1_W[(d - 416) * HID + 2 * lane];
            acc = x.x * q2.x + x.y * q2.y;
        } else if (d == 688) {
            const float2 x = *(const float2*)&glob_b[2 * lane];
            acc = x.x * p2.x + x.y * p2.y;
        } else if (d == 689) {
            const float2 x = *(const float2*)&node_b[2 * lane];
            acc = x.x * p2.x + x.y * p2.y;
        } else { // 690
            const float2 q2 = *(const float2*)&qEE[2 * lane];
            const float2 x1 = *(const float2*)&e1_b[2 * lane];
            const float2 x2 = *(const float2*)&e2_b[2 * lane];
            acc = x1.x * q2.x + x1.y * q2.y + x2.x * p2.x + x2.y * p2.y;
        }
        acc = red64(acc);
        if (lane == 63) ws[d] = acc;
    }
}

// 2032 blocks x 256 threads, 4 roles by bid; all roles co-resident per CU.
// 2-way unrolled: each half-wave keeps 2 independent rows in flight.
__global__ __launch_bounds__(256) void work_kernel(
    const float* __restrict__ nodes, const float* __restrict__ globs,
    const float* __restrict__ edges,
    const float* __restrict__ ag, const float* __restrict__ an,
    const float* __restrict__ ae,
    const int* __restrict__ E, float* __restrict__ ws)
{
    const int t = threadIdx.x, hw = t >> 5, s = t & 31;  // 8 half-waves/block
    const int bid = blockIdx.x;

    if (bid < NB) {
        // ---- node stream: nodes -> nscal ----
        const float4 fr = *(const float4*)&ws[416 + 4 * s];
        const float4 fc = *(const float4*)&ws[560 + 4 * s];
        const float4 fn = *(const float4*)&ws[144 + 4 * s];
        const int stride = NB * 8;
        for (int h0 = bid * 8 + hw; h0 < N_NODES; h0 += 2 * stride) {
            const int h1 = h0 + stride;
            const float4 x0 = *(const float4*)&nodes[h0 * HID + 4 * s];
            float4 x1 = make_float4(0.f, 0.f, 0.f, 0.f);
            if (h1 < N_NODES) x1 = *(const float4*)&nodes[h1 * HID + 4 * s];
            const float ar0 = red32(dot4(x0, fr));
            const float ac0 = red32(dot4(x0, fc));
            const float az0 = red32(dot4(x0, fn));
            const float ar1 = red32(dot4(x1, fr));
            const float ac1 = red32(dot4(x1, fc));
            const float az1 = red32(dot4(x1, fn));
            if (s == 31) {
                *(float4*)&ws[NSCAL_OFF + 4 * h0] = make_float4(ar0, ac0, az0, 0.f);
                if (h1 < N_NODES)
                    *(float4*)&ws[NSCAL_OFF + 4 * h1] = make_float4(ar1, ac1, az1, 0.f);
            }
        }
    } else if (bid < NB + EB) {
        // ---- edge gather: edges[E[g]] -> escal (E prefetch, 2 in flight) ----
        const int eb = bid - NB;
        const float4 q4 = *(const float4*)&ws[288 + 4 * s];
        const int stride = EB * 8;
        int g = eb * 8 + hw;
        int e0 = (g < N_PER) ? E[g] : 0;
        int e1 = (g + stride < N_PER) ? E[g + stride] : 0;
        while (g < N_PER) {
            const int gn = g + 2 * stride;
            const int en0 = (gn < N_PER) ? E[gn] : 0;
            const int en1 = (gn + stride < N_PER) ? E[gn + stride] : 0;
            const float4 x0 = *(const float4*)&edges[e0 * HID + 4 * s];
            float4 x1 = make_float4(0.f, 0.f, 0.f, 0.f);
            if (g + stride < N_PER) x1 = *(const float4*)&edges[e1 * HID + 4 * s];
            const float a0 = red32(dot4(x0, q4));
            const float a1 = red32(dot4(x1, q4));
            if (s == 31) {
                ws[ESCAL_OFF + g] = a0;
                if (g + stride < N_PER) ws[ESCAL_OFF + g + stride] = a1;
            }
            g = gn; e0 = en0; e1 = en1;
        }
    } else if (bid < NB + EB + FB) {
        // ---- feat stream: ag/an/ae -> psum ----
        const int fb = bid - NB - EB;
        const int qg = t >> 4, ql = t & 15;           // 16 actions/block/iter
        for (int a = fb * 16 + qg; a < NUM_ACTIONS; a += FB * 16) {
            const int br = a / 25000;
            const int gl = 4 * (a - br * 25000);
            const float* f = (br == 0) ? ag : (br == 1) ? an : ae;
            const int fbase = (br == 0) ? 128 : (br == 1) ? 272 : 544;
            const float4 fv = *(const float4*)&f[gl * FEAT + 4 * ql];
            const float4 wf = *(const float4*)&ws[fbase + 4 * (ql & 3)];
            const float p = red16(dot4(fv, wf));
            if (ql == 15) ws[PSUM_OFF + a] = p;
        }
    } else {
        // ---- gscal: 512 graphs ----
        const int gb = bid - NB - EB - FB;  // 0..15
        const float4 g4 = *(const float4*)&ws[4 * s];
        for (int u = gb * 8 + hw; u < N_GRAPHS; u += GB * 8) {
            const float4 x = *(const float4*)&globs[u * HID + 4 * s];
            const float a = red32(dot4(x, g4));
            if (s == 31) ws[GSCAL_OFF + u] = a;
        }
    }
}

// One lane per action: coalesced int4/float4 index loads + independent
// scalar table lookups, no cross-lane ops, coalesced store.
__global__ __launch_bounds__(256) void final_kernel(
    const int* __restrict__ row, const int* __restrict__ col,
    const int* __restrict__ U, const int* __restrict__ V,
    const int* __restrict__ E,
    const float* __restrict__ ws, float* __restrict__ out)
{
    const int a = blockIdx.x * 256 + threadIdx.x;
    if (a >= NUM_ACTIONS) return;

    float sum;
    if (a < 25000) {
        const int4 u4 = *(const int4*)&U[4 * a];
        sum = ws[GSCAL_OFF + u4.x] + ws[GSCAL_OFF + u4.y]
            + ws[GSCAL_OFF + u4.z] + ws[GSCAL_OFF + u4.w]
            + 4.f * ws[688];
    } else if (a < 50000) {
        const int4 v4 = *(const int4*)&V[4 * (a - 25000)];
        sum = ws[NSCAL_OFF + 4 * v4.x + 2] + ws[NSCAL_OFF + 4 * v4.y + 2]
            + ws[NSCAL_OFF + 4 * v4.z + 2] + ws[NSCAL_OFF + 4 * v4.w + 2]
            + 4.f * ws[689];
    } else {
        const int g = 4 * (a - 50000);
        const int4 e4 = *(const int4*)&E[g];
        const float4 es = *(const float4*)&ws[ESCAL_OFF + g];
        sum = es.x + es.y + es.z + es.w + 4.f * ws[690];
        sum += ws[NSCAL_OFF + 4 * row[e4.x] + 0] + ws[NSCAL_OFF + 4 * col[e4.x] + 1];
        sum += ws[NSCAL_OFF + 4 * row[e4.y] + 0] + ws[NSCAL_OFF + 4 * col[e4.y] + 1];
        sum += ws[NSCAL_OFF + 4 * row[e4.z] + 0] + ws[NSCAL_OFF + 4 * col[e4.z] + 1];
        sum += ws[NSCAL_OFF + 4 * row[e4.w] + 0] + ws[NSCAL_OFF + 4 * col[e4.w] + 1];
    }
    out[a] = sum + ws[PSUM_OFF + a] + ws[691];
}

extern "C" void kernel_launch(void* const* d_in, const int* in_sizes, int n_in,
                              void* d_out, int out_size, void* d_ws, size_t ws_size,
                              hipStream_t stream)
{
    const float* globs  = (const float*)d_in[0];
    const float* nodes  = (const float*)d_in[1];
    const float* edges  = (const float*)d_in[2];
    const float* ag     = (const float*)d_in[3];
    const float* an     = (const float*)d_in[4];
    const float* ae     = (const float*)d_in[5];
    const float* glob_W = (const float*)d_in[6];
    const float* glob_b = (const float*)d_in[7];
    const float* node_W = (const float*)d_in[8];
    const float* node_b = (const float*)d_in[9];
    const float* e1_W   = (const float*)d_in[10];
    const float* e1_b   = (const float*)d_in[11];
    const float* e2_W   = (const float*)d_in[12];
    const float* e2_b   = (const float*)d_in[13];
    const float* pol_W  = (const float*)d_in[14];
    const float* pol_b  = (const float*)d_in[15];
    const int*   row    = (const int*)d_in[16];
    const int*   col    = (const int*)d_in[17];
    const int*   U      = (const int*)d_in[18];
    const int*   V      = (const int*)d_in[20];
    const int*   E      = (const int*)d_in[22];

    float* ws  = (float*)d_ws;
    float* out = (float*)d_out;

    hipLaunchKernelGGL(fold_kernel, dim3(44), dim3(1024), 0, stream,
                       glob_W, glob_b, node_W, node_b, e1_W, e1_b, e2_W, e2_b,
                       pol_W, pol_b, ws);
    hipLaunchKernelGGL(work_kernel, dim3(WORK_BLOCKS), dim3(256), 0, stream,
                       nodes, globs, edges, ag, an, ae, E, ws);
    hipLaunchKernelGGL(final_kernel, dim3((NUM_ACTIONS + 255) / 256), dim3(256),
                       0, stream, row, col, U, V, E, ws, out);
}

// Round 11
// 37.014 us; speedup vs baseline: 1.0391x; 1.0391x over previous
//
#include <hip/hip_runtime.h>

#define HID 128
#define FEAT 16
#define N_PER 100000
#define NUM_ACTIONS 75000
#define N_NODES 100000
#define N_GRAPHS 512

// ws float layout:
// [0..143]   wg   (globs part 0..127, feat part 128..143)
// [144..287] wn   (nodes part 144..271, feat part 272..287)
// [288..415] qe
// [416..687] w1   (row 416..543, feat 544..559, col 560..687)
// [688] cg [689] cn [690] ce [691] pb
// [NSCAL_OFF + 4h]  nscal(h): (x=nodes.wr, y=nodes.wc, z=nodes.wn)
// [GSCAL_OFF + u]   gscal(u) = globs[u].wg
// [ESCAL_OFF + g]   escal(g) = edges[E[g]].qe
// [PSUM_OFF + a]    psum(a)  = per-action feat-dot partial
#define NSCAL_OFF 1024
#define GSCAL_OFF (NSCAL_OFF + 4 * N_NODES)
#define ESCAL_OFF (GSCAL_OFF + N_GRAPHS)
#define PSUM_OFF  (ESCAL_OFF + N_PER)

#define NB 696
#define EB 1064
#define FB 256
#define GB 16
#define WORK_BLOCKS (NB + EB + FB + GB)

typedef float f4 __attribute__((ext_vector_type(4)));

__device__ __forceinline__ float dot4v(f4 a, f4 b) {
    const f4 m = a * b;
    return m.x + m.y + m.z + m.w;
}
__device__ __forceinline__ float dot4(float4 a, float4 b) {
    return a.x * b.x + a.y * b.y + a.z * b.z + a.w * b.w;
}

// ---- DPP sum reductions (VALU-only, no LDS pipe) ----
template <int CTRL>
__device__ __forceinline__ float dpp_mov(float x) {
    return __int_as_float(__builtin_amdgcn_update_dpp(
        0, __float_as_int(x), CTRL, 0xF, 0xF, true));
}
__device__ __forceinline__ float red16(float x) {
    x += dpp_mov<0x111>(x);   // row_shr:1
    x += dpp_mov<0x112>(x);   // row_shr:2
    x += dpp_mov<0x114>(x);   // row_shr:4
    x += dpp_mov<0x118>(x);   // row_shr:8
    return x;                 // valid in lane 15 (mod 16)
}
__device__ __forceinline__ float red32(float x) {
    x = red16(x);
    x += dpp_mov<0x142>(x);   // row_bcast:15
    return x;                 // valid in lane 31 (mod 32)
}
__device__ __forceinline__ float red64(float x) {
    x = red32(x);
    x += dpp_mov<0x143>(x);   // row_bcast:31
    return x;                 // valid in lane 63
}

// 44 blocks x 1024 threads (proven R6 version). Blocks 26..43 build qEE in
// LDS; each wave then does <=1 of the 692 folded dots.
__global__ __launch_bounds__(1024) void fold_kernel(
    const float* __restrict__ glob_W, const float* __restrict__ glob_b,
    const float* __restrict__ node_W, const float* __restrict__ node_b,
    const float* __restrict__ e1_W,  const float* __restrict__ e1_b,
    const float* __restrict__ e2_W,  const float* __restrict__ e2_b,
    const float* __restrict__ pol_W, const float* __restrict__ pol_b,
    float* __restrict__ ws)
{
    __shared__ float qEE[HID];
    const int t = threadIdx.x, wave = t >> 6, lane = t & 63;
    const int bid = blockIdx.x;

    const bool needq = (bid >= 26 && bid <= 43);
    if (needq) {
        const int hw = t >> 5, s = t & 31;
        const float4 p4 = *(const float4*)&pol_W[4 * s];
        #pragma unroll
        for (int r = 0; r < 4; ++r) {
            const int k = hw + 32 * r;
            const float4 x = *(const float4*)&e2_W[(HID + k) * HID + 4 * s];
            float acc = red32(dot4(x, p4));
            if (s == 31) qEE[k] = acc;
        }
        __syncthreads();
    }

    const float2 p2 = *(const float2*)&pol_W[2 * lane];
    const int d = bid * 16 + wave;
    if (d == 691) {
        if (lane == 0) ws[691] = pol_b[0];
    } else if (d < 692) {
        float acc;
        if (d < 144) {
            const float2 x = *(const float2*)&glob_W[d * HID + 2 * lane];
            acc = x.x * p2.x + x.y * p2.y;
        } else if (d < 288) {
            const float2 x = *(const float2*)&node_W[(d - 144) * HID + 2 * lane];
            acc = x.x * p2.x + x.y * p2.y;
        } else if (d < 416) {
            const float2 x = *(const float2*)&e2_W[(d - 288) * HID + 2 * lane];
            acc = x.x * p2.x + x.y * p2.y;
        } else if (d < 688) {
            const float2 q2 = *(const float2*)&qEE[2 * lane];
            const float2 x  = *(const float2*)&e1_W[(d - 416) * HID + 2 * lane];
            acc = x.x * q2.x + x.y * q2.y;
        } else if (d == 688) {
            const float2 x = *(const float2*)&glob_b[2 * lane];
            acc = x.x * p2.x + x.y * p2.y;
        } else if (d == 689) {
            const float2 x = *(const float2*)&node_b[2 * lane];
            acc = x.x * p2.x + x.y * p2.y;
        } else { // 690
            const float2 q2 = *(const float2*)&qEE[2 * lane];
            const float2 x1 = *(const float2*)&e1_b[2 * lane];
            const float2 x2 = *(const float2*)&e2_b[2 * lane];
            acc = x1.x * q2.x + x1.y * q2.y + x2.x * p2.x + x2.y * p2.y;
        }
        acc = red64(acc);
        if (lane == 63) ws[d] = acc;
    }
}

// 2032 blocks x 256 threads, 4 roles by bid; all roles co-resident per CU.
// Read-once streams use nontemporal loads so the edges gather keeps L2/L3.
__global__ __launch_bounds__(256) void work_kernel(
    const float* __restrict__ nodes, const float* __restrict__ globs,
    const float* __restrict__ edges,
    const float* __restrict__ ag, const float* __restrict__ an,
    const float* __restrict__ ae,
    const int* __restrict__ E, float* __restrict__ ws)
{
    const int t = threadIdx.x, hw = t >> 5, s = t & 31;  // 8 half-waves/block
    const int bid = blockIdx.x;

    if (bid < NB) {
        // ---- node stream: nodes -> nscal (nt loads, read-once) ----
        const f4 fr = *(const f4*)&ws[416 + 4 * s];
        const f4 fc = *(const f4*)&ws[560 + 4 * s];
        const f4 fn = *(const f4*)&ws[144 + 4 * s];
        for (int h = bid * 8 + hw; h < N_NODES; h += NB * 8) {
            const f4 x = __builtin_nontemporal_load((const f4*)&nodes[h * HID + 4 * s]);
            const float ar = red32(dot4v(x, fr));
            const float ac = red32(dot4v(x, fc));
            const float az = red32(dot4v(x, fn));
            if (s == 31)
                *(float4*)&ws[NSCAL_OFF + 4 * h] = make_float4(ar, ac, az, 0.f);
        }
    } else if (bid < NB + EB) {
        // ---- edge gather: edges[E[g]] -> escal (E prefetch; cached loads) ----
        const int eb = bid - NB;
        const f4 q4 = *(const f4*)&ws[288 + 4 * s];
        int g = eb * 8 + hw;
        const int stride = EB * 8;
        int e = (g < N_PER) ? E[g] : 0;
        while (g < N_PER) {
            const int gn = g + stride;
            const int en = (gn < N_PER) ? E[gn] : 0;
            const f4 x = *(const f4*)&edges[e * HID + 4 * s];
            const float acc = red32(dot4v(x, q4));
            if (s == 31) ws[ESCAL_OFF + g] = acc;
            g = gn; e = en;
        }
    } else if (bid < NB + EB + FB) {
        // ---- feat stream: ag/an/ae -> psum (nt loads, read-once) ----
        const int fb = bid - NB - EB;
        const int qg = t >> 4, ql = t & 15;           // 16 actions/block/iter
        for (int a = fb * 16 + qg; a < NUM_ACTIONS; a += FB * 16) {
            const int br = a / 25000;
            const int gl = 4 * (a - br * 25000);
            const float* f = (br == 0) ? ag : (br == 1) ? an : ae;
            const int fbase = (br == 0) ? 128 : (br == 1) ? 272 : 544;
            const f4 fv = __builtin_nontemporal_load((const f4*)&f[gl * FEAT + 4 * ql]);
            const f4 wf = *(const f4*)&ws[fbase + 4 * (ql & 3)];
            const float p = red16(dot4v(fv, wf));
            if (ql == 15) ws[PSUM_OFF + a] = p;
        }
    } else {
        // ---- gscal: 512 graphs ----
        const int gb = bid - NB - EB - FB;  // 0..15
        const f4 g4 = *(const f4*)&ws[4 * s];
        for (int u = gb * 8 + hw; u < N_GRAPHS; u += GB * 8) {
            const f4 x = __builtin_nontemporal_load((const f4*)&globs[u * HID + 4 * s]);
            const float a = red32(dot4v(x, g4));
            if (s == 31) ws[GSCAL_OFF + u] = a;
        }
    }
}

// One lane per action row (300K): 1-3 scalar table lookups, group-of-4 DPP
// sum, writing lane adds psum + constants and stores out[a].
__global__ __launch_bounds__(256) void final_kernel(
    const int* __restrict__ row, const int* __restrict__ col,
    const int* __restrict__ U, const int* __restrict__ V,
    const int* __restrict__ E,
    const float* __restrict__ ws, float* __restrict__ out)
{
    const int r = blockIdx.x * 256 + threadIdx.x;
    if (r >= 3 * N_PER) return;
    const int br = r / N_PER;            // 0=glob 1=node 2=edge
    const int g  = r - br * N_PER;

    float look, cb;
    if (br == 0) {
        look = ws[GSCAL_OFF + U[g]];
        cb = ws[688];
    } else if (br == 1) {
        look = ws[NSCAL_OFF + 4 * V[g] + 2];
        cb = ws[689];
    } else {
        const int e = E[g];
        look = ws[ESCAL_OFF + g]
             + ws[NSCAL_OFF + 4 * row[e] + 0]
             + ws[NSCAL_OFF + 4 * col[e] + 1];
        cb = ws[690];
    }
    // sum within groups of 4 lanes (valid in lane 3 mod 4)
    float s4 = look;
    s4 += dpp_mov<0x111>(s4);
    s4 += dpp_mov<0x112>(s4);
    if ((threadIdx.x & 3) == 3) {
        const int a = r >> 2;            // global action id (layout matches)
        out[a] = s4 + ws[PSUM_OFF + a] + 4.f * cb + ws[691];
    }
}

extern "C" void kernel_launch(void* const* d_in, const int* in_sizes, int n_in,
                              void* d_out, int out_size, void* d_ws, size_t ws_size,
                              hipStream_t stream)
{
    const float* globs  = (const float*)d_in[0];
    const float* nodes  = (const float*)d_in[1];
    const float* edges  = (const float*)d_in[2];
    const float* ag     = (const float*)d_in[3];
    const float* an     = (const float*)d_in[4];
    const float* ae     = (const float*)d_in[5];
    const float* glob_W = (const float*)d_in[6];
    const float* glob_b = (const float*)d_in[7];
    const float* node_W = (const float*)d_in[8];
    const float* node_b = (const float*)d_in[9];
    const float* e1_W   = (const float*)d_in[10];
    const float* e1_b   = (const float*)d_in[11];
    const float* e2_W   = (const float*)d_in[12];
    const float* e2_b   = (const float*)d_in[13];
    const float* pol_W  = (const float*)d_in[14];
    const float* pol_b  = (const float*)d_in[15];
    const int*   row    = (const int*)d_in[16];
    const int*   col    = (const int*)d_in[17];
    const int*   U      = (const int*)d_in[18];
    const int*   V      = (const int*)d_in[20];
    const int*   E      = (const int*)d_in[22];

    float* ws  = (float*)d_ws;
    float* out = (float*)d_out;

    hipLaunchKernelGGL(fold_kernel, dim3(44), dim3(1024), 0, stream,
                       glob_W, glob_b, node_W, node_b, e1_W, e1_b, e2_W, e2_b,
                       pol_W, pol_b, ws);
    hipLaunchKernelGGL(work_kernel, dim3(WORK_BLOCKS), dim3(256), 0, stream,
                       nodes, globs, edges, ag, an, ae, E, ws);
    hipLaunchKernelGGL(final_kernel, dim3((3 * N_PER + 255) / 256), dim3(256),
                       0, stream, row, col, U, V, E, ws, out);
}

// Round 12
// 35.651 us; speedup vs baseline: 1.0788x; 1.0382x over previous
//
#include <hip/hip_runtime.h>

#define HID 128
#define FEAT 16
#define N_PER 100000
#define NUM_ACTIONS 75000
#define N_NODES 100000
#define N_GRAPHS 512

// ws float layout:
// [0..143]   wg   (globs part 0..127, feat part 128..143)
// [144..287] wn   (nodes part 144..271, feat part 272..287)
// [288..415] qe
// [416..687] w1   (row 416..543, feat 544..559, col 560..687)
// [688] cg [689] cn [690] ce [691] pb
// [NSCAL_OFF + 4h]  nscal(h): (x=nodes.wr, y=nodes.wc, z=nodes.wn)
// [GSCAL_OFF + u]   gscal(u) = globs[u].wg
// [ESCAL_OFF + g]   escal(g) = edges[E[g]].qe
// [PSUM_OFF + a]    psum(a)  = per-action feat-dot partial
#define NSCAL_OFF 1024
#define GSCAL_OFF (NSCAL_OFF + 4 * N_NODES)
#define ESCAL_OFF (GSCAL_OFF + N_GRAPHS)
#define PSUM_OFF  (ESCAL_OFF + N_PER)

#define NB 760
#define EB 968
#define FB 288
#define GB 16
#define WORK_BLOCKS (NB + EB + FB + GB)

__device__ __forceinline__ float dot4(float4 a, float4 b) {
    return a.x * b.x + a.y * b.y + a.z * b.z + a.w * b.w;
}

// ---- DPP sum reductions (VALU-only, no LDS pipe) ----
template <int CTRL>
__device__ __forceinline__ float dpp_mov(float x) {
    return __int_as_float(__builtin_amdgcn_update_dpp(
        0, __float_as_int(x), CTRL, 0xF, 0xF, true));
}
__device__ __forceinline__ float red16(float x) {
    x += dpp_mov<0x111>(x);   // row_shr:1
    x += dpp_mov<0x112>(x);   // row_shr:2
    x += dpp_mov<0x114>(x);   // row_shr:4
    x += dpp_mov<0x118>(x);   // row_shr:8
    return x;                 // valid in lane 15 (mod 16)
}
__device__ __forceinline__ float red32(float x) {
    x = red16(x);
    x += dpp_mov<0x142>(x);   // row_bcast:15
    return x;                 // valid in lane 31 (mod 32)
}
__device__ __forceinline__ float red64(float x) {
    x = red32(x);
    x += dpp_mov<0x143>(x);   // row_bcast:31
    return x;                 // valid in lane 63
}

// 44 blocks x 1024 threads (R6 version, proven). Blocks 26..43 build qEE in
// LDS; each wave then does <=1 of the 692 folded dots.
__global__ __launch_bounds__(1024) void fold_kernel(
    const float* __restrict__ glob_W, const float* __restrict__ glob_b,
    const float* __restrict__ node_W, const float* __restrict__ node_b,
    const float* __restrict__ e1_W,  const float* __restrict__ e1_b,
    const float* __restrict__ e2_W,  const float* __restrict__ e2_b,
    const float* __restrict__ pol_W, const float* __restrict__ pol_b,
    float* __restrict__ ws)
{
    __shared__ float qEE[HID];
    const int t = threadIdx.x, wave = t >> 6, lane = t & 63;
    const int bid = blockIdx.x;

    const bool needq = (bid >= 26 && bid <= 43);
    if (needq) {
        const int hw = t >> 5, s = t & 31;
        const float4 p4 = *(const float4*)&pol_W[4 * s];
        #pragma unroll
        for (int r = 0; r < 4; ++r) {
            const int k = hw + 32 * r;
            const float4 x = *(const float4*)&e2_W[(HID + k) * HID + 4 * s];
            float acc = red32(dot4(x, p4));
            if (s == 31) qEE[k] = acc;
        }
        __syncthreads();
    }

    const float2 p2 = *(const float2*)&pol_W[2 * lane];
    const int d = bid * 16 + wave;
    if (d == 691) {
        if (lane == 0) ws[691] = pol_b[0];
    } else if (d < 692) {
        float acc;
        if (d < 144) {
            const float2 x = *(const float2*)&glob_W[d * HID + 2 * lane];
            acc = x.x * p2.x + x.y * p2.y;
        } else if (d < 288) {
            const float2 x = *(const float2*)&node_W[(d - 144) * HID + 2 * lane];
            acc = x.x * p2.x + x.y * p2.y;
        } else if (d < 416) {
            const float2 x = *(const float2*)&e2_W[(d - 288) * HID + 2 * lane];
            acc = x.x * p2.x + x.y * p2.y;
        } else if (d < 688) {
            const float2 q2 = *(const float2*)&qEE[2 * lane];
            const float2 x  = *(const float2*)&e1_W[(d - 416) * HID + 2 * lane];
            acc = x.x * q2.x + x.y * q2.y;
        } else if (d == 688) {
            const float2 x = *(const float2*)&glob_b[2 * lane];
            acc = x.x * p2.x + x.y * p2.y;
        } else if (d == 689) {
            const float2 x = *(const float2*)&node_b[2 * lane];
            acc = x.x * p2.x + x.y * p2.y;
        } else { // 690
            const float2 q2 = *(const float2*)&qEE[2 * lane];
            const float2 x1 = *(const float2*)&e1_b[2 * lane];
            const float2 x2 = *(const float2*)&e2_b[2 * lane];
            acc = x1.x * q2.x + x1.y * q2.y + x2.x * p2.x + x2.y * p2.y;
        }
        acc = red64(acc);
        if (lane == 63) ws[d] = acc;
    }
}

// 2032 blocks x 256 threads, 4 roles by bid; all blocks co-resident.
// node: stream nodes -> nscal.  edge: gather edges[E[g]] -> escal.
// feat: stream ag/an/ae -> per-action psum.  gscal: 512 graphs.
__global__ __launch_bounds__(256) void work_kernel(
    const float* __restrict__ nodes, const float* __restrict__ globs,
    const float* __restrict__ edges,
    const float* __restrict__ ag, const float* __restrict__ an,
    const float* __restrict__ ae,
    const int* __restrict__ E, float* __restrict__ ws)
{
    const int t = threadIdx.x, hw = t >> 5, s = t & 31;  // 8 half-waves/block
    const int bid = blockIdx.x;

    if (bid < NB) {
        const float4 fr = *(const float4*)&ws[416 + 4 * s];
        const float4 fc = *(const float4*)&ws[560 + 4 * s];
        const float4 fn = *(const float4*)&ws[144 + 4 * s];
        for (int h = bid * 8 + hw; h < N_NODES; h += NB * 8) {
            const float4 x = *(const float4*)&nodes[h * HID + 4 * s];
            const float ar = red32(dot4(x, fr));
            const float ac = red32(dot4(x, fc));
            const float az = red32(dot4(x, fn));
            if (s == 31)
                *(float4*)&ws[NSCAL_OFF + 4 * h] = make_float4(ar, ac, az, 0.f);
        }
    } else if (bid < NB + EB) {
        const int eb = bid - NB;
        const float4 q4 = *(const float4*)&ws[288 + 4 * s];
        int g = eb * 8 + hw;
        const int stride = EB * 8;
        int e = (g < N_PER) ? E[g] : 0;
        while (g < N_PER) {
            const int gn = g + stride;
            const int en = (gn < N_PER) ? E[gn] : 0;
            const float4 x = *(const float4*)&edges[e * HID + 4 * s];
            const float acc = red32(dot4(x, q4));
            if (s == 31) ws[ESCAL_OFF + g] = acc;
            g = gn; e = en;
        }
    } else if (bid < NB + EB + FB) {
        const int fb = bid - NB - EB;
        const int qg = t >> 4, ql = t & 15;           // 16 actions/block/iter
        for (int a = fb * 16 + qg; a < NUM_ACTIONS; a += FB * 16) {
            const int br = a / 25000;
            const int gl = 4 * (a - br * 25000);
            const float* f = (br == 0) ? ag : (br == 1) ? an : ae;
            const int fbase = (br == 0) ? 128 : (br == 1) ? 272 : 544;
            const float4 fv = *(const float4*)&f[gl * FEAT + 4 * ql];
            const float4 wf = *(const float4*)&ws[fbase + 4 * (ql & 3)];
            const float p = red16(dot4(fv, wf));
            if (ql == 15) ws[PSUM_OFF + a] = p;
        }
    } else {
        const int gb = bid - NB - EB - FB;  // 0..15
        const float4 g4 = *(const float4*)&ws[4 * s];
        for (int u = gb * 8 + hw; u < N_GRAPHS; u += GB * 8) {
            const float4 x = *(const float4*)&globs[u * HID + 4 * s];
            const float a = red32(dot4(x, g4));
            if (s == 31) ws[GSCAL_OFF + u] = a;
        }
    }
}

// One lane per action row (300K): 1-3 scalar table lookups, group-of-4 DPP
// sum, writing lane adds psum + constants and stores out[a].
__global__ __launch_bounds__(256) void final_kernel(
    const int* __restrict__ row, const int* __restrict__ col,
    const int* __restrict__ U, const int* __restrict__ V,
    const int* __restrict__ E,
    const float* __restrict__ ws, float* __restrict__ out)
{
    const int r = blockIdx.x * 256 + threadIdx.x;
    if (r >= 3 * N_PER) return;
    const int br = r / N_PER;            // 0=glob 1=node 2=edge
    const int g  = r - br * N_PER;

    float look, cb;
    if (br == 0) {
        look = ws[GSCAL_OFF + U[g]];
        cb = ws[688];
    } else if (br == 1) {
        look = ws[NSCAL_OFF + 4 * V[g] + 2];
        cb = ws[689];
    } else {
        const int e = E[g];
        look = ws[ESCAL_OFF + g]
             + ws[NSCAL_OFF + 4 * row[e] + 0]
             + ws[NSCAL_OFF + 4 * col[e] + 1];
        cb = ws[690];
    }
    // sum within groups of 4 lanes (valid in lane 3 mod 4)
    float s4 = look;
    s4 += dpp_mov<0x111>(s4);
    s4 += dpp_mov<0x112>(s4);
    if ((threadIdx.x & 3) == 3) {
        const int a = r >> 2;            // global action id (layout matches)
        out[a] = s4 + ws[PSUM_OFF + a] + 4.f * cb + ws[691];
    }
}

extern "C" void kernel_launch(void* const* d_in, const int* in_sizes, int n_in,
                              void* d_out, int out_size, void* d_ws, size_t ws_size,
                              hipStream_t stream)
{
    const float* globs  = (const float*)d_in[0];
    const float* nodes  = (const float*)d_in[1];
    const float* edges  = (const float*)d_in[2];
    const float* ag     = (const float*)d_in[3];
    const float* an     = (const float*)d_in[4];
    const float* ae     = (const float*)d_in[5];
    const float* glob_W = (const float*)d_in[6];
    const float* glob_b = (const float*)d_in[7];
    const float* node_W = (const float*)d_in[8];
    const float* node_b = (const float*)d_in[9];
    const float* e1_W   = (const float*)d_in[10];
    const float* e1_b   = (const float*)d_in[11];
    const float* e2_W   = (const float*)d_in[12];
    const float* e2_b   = (const float*)d_in[13];
    const float* pol_W  = (const float*)d_in[14];
    const float* pol_b  = (const float*)d_in[15];
    const int*   row    = (const int*)d_in[16];
    const int*   col    = (const int*)d_in[17];
    const int*   U      = (const int*)d_in[18];
    const int*   V      = (const int*)d_in[20];
    const int*   E      = (const int*)d_in[22];

    float* ws  = (float*)d_ws;
    float* out = (float*)d_out;

    hipLaunchKernelGGL(fold_kernel, dim3(44), dim3(1024), 0, stream,
                       glob_W, glob_b, node_W, node_b, e1_W, e1_b, e2_W, e2_b,
                       pol_W, pol_b, ws);
    hipLaunchKernelGGL(work_kernel, dim3(WORK_BLOCKS), dim3(256), 0, stream,
                       nodes, globs, edges, ag, an, ae, E, ws);
    hipLaunchKernelGGL(final_kernel, dim3((3 * N_PER + 255) / 256), dim3(256),
                       0, stream, row, col, U, V, E, ws, out);
}